// Round 1
// baseline (146.501 us; speedup 1.0000x reference)
//
#include <hip/hip_runtime.h>
#include <math.h>

#define BM 32
#define BK 64
#define SPAD 112          // padded sample-column count (100 -> 112)
#define LDA 68            // padded LDS row stride in floats (64 + 4)
#define NTHREADS 256

// ws[0] = sum of per-token losses, ws[1] = valid count (as float)
__global__ __launch_bounds__(NTHREADS, 4)
void ssce_main(const float* __restrict__ pred,
               const int*   __restrict__ labels,
               const float* __restrict__ proj,
               const float* __restrict__ bias,
               const int*   __restrict__ samples,
               float* __restrict__ ws,
               int Btot, int D, int V, int S, float logV1)
{
    __shared__ float sA[BM * LDA];        //  8704 B  pred tile [32][68]
    __shared__ float sQ[SPAD * LDA];      // 30464 B  proj[samples] tile [112][68]; reused for scores
    __shared__ float sLabelScore[BM];
    __shared__ float sBiasS[SPAD];
    __shared__ int   sSamp[SPAD];
    __shared__ int   sLabels[BM];

    const int tid  = threadIdx.x;
    const int tn   = tid & 15;            // 0..15
    const int tm   = tid >> 4;            // 0..15
    const int lane = tid & 63;
    const int w    = tid >> 6;            // wave 0..3
    const int rowBase = blockIdx.x * BM;

    // ---- stage samples / bias / labels ----
    if (tid < SPAD) {
        int s = (tid < S) ? samples[tid] : -1;
        sSamp[tid]  = s;
        sBiasS[tid] = (s >= 0) ? bias[s] : 0.0f;
    }
    if (tid < BM) {
        int gr = rowBase + tid;
        sLabels[tid] = (gr < Btot) ? labels[gr] : -100;
    }
    __syncthreads();

    // ---- per-thread staging pointers ----
    // A tile: each thread stages rows tm and tm+16, cols tn*4..tn*4+3 per chunk
    const float* aSrc0 = pred + (size_t)(rowBase + tm)      * D + tn * 4;
    const float* aSrc1 = pred + (size_t)(rowBase + tm + 16) * D + tn * 4;
    float* aDst0 = &sA[ tm       * LDA + tn * 4];
    float* aDst1 = &sA[(tm + 16) * LDA + tn * 4];

    // Q tile: thread stages sample-rows s = tm + 16*i, i=0..6
    const float* qSrc[7];
    float*       qDst[7];
    #pragma unroll
    for (int i = 0; i < 7; ++i) {
        int s  = tm + 16 * i;
        int sm = (s < S) ? sSamp[s] : -1;
        qSrc[i] = (sm >= 0) ? (proj + (size_t)sm * D + tn * 4) : nullptr;
        qDst[i] = &sQ[s * LDA + tn * 4];
    }

    // label-dot pointers: wave w owns local rows w*8 .. w*8+7
    const float* lPtr[8];
    float lFlag[8];
    #pragma unroll
    for (int j = 0; j < 8; ++j) {
        int lab = sLabels[w * 8 + j];
        lPtr[j]  = proj + (size_t)(lab >= 0 ? lab : 0) * D + lane;
        lFlag[j] = (lab >= 0) ? 1.0f : 0.0f;
    }

    float acc[2][7];
    #pragma unroll
    for (int i = 0; i < 2; ++i)
        #pragma unroll
        for (int j = 0; j < 7; ++j) acc[i][j] = 0.0f;
    float lpart[8];
    #pragma unroll
    for (int j = 0; j < 8; ++j) lpart[j] = 0.0f;

    const int r0 = 2 * tm, r1 = 2 * tm + 1;
    const int nChunks = D / BK;           // 768/64 = 12

    for (int ck = 0; ck < nChunks; ++ck) {
        const int k0 = ck * BK;
        __syncthreads();                  // previous compute done; LDS reusable
        // ---- stage A (2 x float4) ----
        float4 av0 = *(const float4*)(aSrc0 + k0);
        float4 av1 = *(const float4*)(aSrc1 + k0);
        *(float4*)aDst0 = av0;
        *(float4*)aDst1 = av1;
        // ---- stage Q (7 x float4) ----
        #pragma unroll
        for (int i = 0; i < 7; ++i) {
            float4 qv = make_float4(0.f, 0.f, 0.f, 0.f);
            if (qSrc[i]) qv = *(const float4*)(qSrc[i] + k0);
            *(float4*)qDst[i] = qv;
        }
        __syncthreads();                  // tiles visible
        // ---- issue label-row loads early (latency hidden under GEMM) ----
        float pl[8];
        #pragma unroll
        for (int j = 0; j < 8; ++j) pl[j] = lPtr[j][k0] * lFlag[j];
        // ---- register-blocked GEMM: 2 rows x 7 cols ----
        #pragma unroll 4
        for (int kq = 0; kq < BK / 4; ++kq) {
            float4 a0 = *(const float4*)&sA[r0 * LDA + kq * 4];
            float4 a1 = *(const float4*)&sA[r1 * LDA + kq * 4];
            #pragma unroll
            for (int j = 0; j < 7; ++j) {
                float4 b = *(const float4*)&sQ[(tn + 16 * j) * LDA + kq * 4];
                acc[0][j] += a0.x * b.x + a0.y * b.y + a0.z * b.z + a0.w * b.w;
                acc[1][j] += a1.x * b.x + a1.y * b.y + a1.z * b.z + a1.w * b.w;
            }
        }
        // ---- label-dot FMAs against staged pred tile ----
        #pragma unroll
        for (int j = 0; j < 8; ++j)
            lpart[j] += sA[(w * 8 + j) * LDA + lane] * pl[j];
    }

    // ---- reduce label dots across the wave ----
    #pragma unroll
    for (int j = 0; j < 8; ++j) {
        float v = lpart[j];
        #pragma unroll
        for (int off = 32; off > 0; off >>= 1)
            v += __shfl_down(v, off);
        if (lane == 0) {
            int r   = w * 8 + j;
            int lab = sLabels[r];
            sLabelScore[r] = v + ((lab >= 0) ? bias[lab] : 0.0f);
        }
    }
    __syncthreads();                      // everyone done reading sQ & sA

    // ---- dump accumulators to LDS scores[32][113] (overlay on sQ) ----
    float* scores = sQ;
    #pragma unroll
    for (int i = 0; i < 2; ++i)
        #pragma unroll
        for (int j = 0; j < 7; ++j)
            scores[(2 * tm + i) * 113 + (tn + 16 * j)] = acc[i][j];
    __syncthreads();

    // ---- per-row softmax CE (threads 0..31, one row each) ----
    float pt = 0.0f, vc = 0.0f;
    if (tid < BM && rowBase + tid < Btot) {
        int  lab   = sLabels[tid];
        bool valid = (lab != -100);
        int  cnt   = 0;
        if (valid)
            for (int s = 0; s < S; ++s) cnt += (sSamp[s] == lab) ? 1 : 0;
        float corr = logV1 - __logf((float)(S - cnt));
        float ls   = sLabelScore[tid];
        float m    = ls;
        for (int s = 0; s < S; ++s) {
            float v = scores[tid * 113 + s] + sBiasS[s] + corr;
            if (valid && sSamp[s] == lab) v -= 1000000.0f;
            m = fmaxf(m, v);
        }
        float se = __expf(ls - m);
        for (int s = 0; s < S; ++s) {
            float v = scores[tid * 113 + s] + sBiasS[s] + corr;
            if (valid && sSamp[s] == lab) v -= 1000000.0f;
            se += __expf(v - m);
        }
        float per_tok = m - ls + __logf(se);
        if (valid) { pt = per_tok; vc = 1.0f; }
    }
    // ---- block reduce in wave 0 (lanes >=32 hold zeros) ----
    if (tid < 64) {
        #pragma unroll
        for (int off = 32; off > 0; off >>= 1) {
            pt += __shfl_down(pt, off);
            vc += __shfl_down(vc, off);
        }
        if (tid == 0) {
            atomicAdd(&ws[0], pt);
            atomicAdd(&ws[1], vc);
        }
    }
}

__global__ void ssce_final(const float* __restrict__ ws, float* __restrict__ out)
{
    out[0] = ws[0] / fmaxf(ws[1], 1.0f);
}

extern "C" void kernel_launch(void* const* d_in, const int* in_sizes, int n_in,
                              void* d_out, int out_size, void* d_ws, size_t ws_size,
                              hipStream_t stream)
{
    const float* pred    = (const float*)d_in[0];
    const int*   labels  = (const int*)  d_in[1];
    const float* proj    = (const float*)d_in[2];
    const float* bias    = (const float*)d_in[3];
    const int*   samples = (const int*)  d_in[4];

    const int B = in_sizes[1];            // labels count
    const int V = in_sizes[3];            // bias count = n_classes
    const int S = in_sizes[4];            // num samples
    const int D = in_sizes[0] / B;        // feature dim

    float logV1 = logf((float)(V - 1));
    float* ws = (float*)d_ws;

    hipMemsetAsync(d_ws, 0, 2 * sizeof(float), stream);

    const int grid = (B + BM - 1) / BM;
    ssce_main<<<grid, NTHREADS, 0, stream>>>(pred, labels, proj, bias, samples,
                                             ws, B, D, V, S, logV1);
    ssce_final<<<1, 1, 0, stream>>>(ws, (float*)d_out);
}